// Round 2
// baseline (1260.992 us; speedup 1.0000x reference)
//
#include <hip/hip_runtime.h>
#include <math.h>

#define WIDTH 256
#define PTS 32             // points per block
#define CPLANE 40960       // halves per component plane: 5v * 32kb * 32p * 8
#define WPLANE 65536       // halves per weight component plane: 8Mt * 16s * 64lane * 8

typedef _Float16 f16x8 __attribute__((ext_vector_type(8)));
typedef _Float16 f16x4 __attribute__((ext_vector_type(4)));
typedef __fp16   h16x2 __attribute__((ext_vector_type(2)));   // cvt_pkrtz return type
typedef float    f32x16 __attribute__((ext_vector_type(16)));

// fp32 -> fp16 hi + fp16 lo (2-split, covers ~22-24 mantissa bits)
__device__ __forceinline__ void split2(float f, _Float16& h, _Float16& l) {
    h = (_Float16)f;
    l = (_Float16)(f - (float)h);
}
// z=tanh(u), s=1-z^2 = 4t/(1+t)^2 with t=exp(-2|u|): no cancellation in saturation.
// rcp via v_rcp_f32 (1 ulp) instead of IEEE divide sequence (~10 instrs).
__device__ __forceinline__ void tanh_s(float u, float& z, float& s) {
    const float t = __expf(-2.0f * fabsf(u));
    const float r = __builtin_amdgcn_rcpf(1.0f + t);
    const float zm = (1.0f - t) * r;
    z = copysignf(zm, u);
    s = 4.0f * t * r * r;
}

// Pre-split w1..w5 into fp16 hi/lo, transposed + packed in 32x32x16 MFMA A-frag
// order: wt2[(l*2+c)*WPLANE + ((Mt*16+s)*64 + lane)*8 + i] = comp_c(W[k][j]),
// j = Mt*32 + (lane&31), k = s*16 + (lane>>5)*8 + i.
__global__ void prep_w_kernel(const float* __restrict__ w1, const float* __restrict__ w2,
                              const float* __restrict__ w3, const float* __restrict__ w4,
                              const float* __restrict__ w5, _Float16* __restrict__ wt2)
{
    const int idx = blockIdx.x * blockDim.x + threadIdx.x;
    if (idx >= 5 * 8 * 16 * 64) return;
    const int lane = idx & 63;
    const int s    = (idx >> 6) & 15;
    const int Mt   = (idx >> 10) & 7;
    const int l    = idx >> 13;
    const float* Wsrc[5] = { w1, w2, w3, w4, w5 };
    const float* W = Wsrc[l];
    const int j  = Mt * 32 + (lane & 31);
    const int k0 = s * 16 + (lane >> 5) * 8;
    f16x8 vh, vl;
    #pragma unroll
    for (int i = 0; i < 8; ++i) {
        _Float16 h, lo;
        split2(W[(k0 + i) * WIDTH + j], h, lo);
        vh[i] = h; vl[i] = lo;
    }
    const int fo = ((Mt * 16 + s) * 64 + lane) * 8;
    *(f16x8*)(wt2 + (l * 2 + 0) * WPLANE + fo) = vh;
    *(f16x8*)(wt2 + (l * 2 + 1) * WPLANE + fo) = vl;
}

// 256 threads = 4 waves, 1 wave/SIMD, 1 block/CU (160 KiB LDS).
// 32 points/block; N-tile v = chain, M-tile = 32 features (2 per wave).
// Z layout: Zs[c*CPLANE + ((v*32 + (k>>3))*32 + p)*8 + (k&7)], p = point.
// B-frag read (lane): col p = lane&31, k = s*16 + (lane>>5)*8 + i ->
//   halves offset ((v*32 + s*2 + (lane>>5))*32 + (lane&31))*8 : 1024 B
//   contiguous per wave -> conflict-free b128.
__global__ __launch_bounds__(256, 1)
void pde_mfma_kernel(const float* __restrict__ xyt,
                     const float* __restrict__ w0, const float* __restrict__ b0,
                     const float* __restrict__ b1, const float* __restrict__ b2,
                     const float* __restrict__ b3, const float* __restrict__ b4,
                     const float* __restrict__ b5,
                     const float* __restrict__ w6, const float* __restrict__ b6,
                     const _Float16* __restrict__ wt2,
                     float* __restrict__ out)
{
    __shared__ _Float16 Zs[2 * CPLANE];   // 163840 B = full LDS
    float* redf = (float*)Zs;             // aliased reduction scratch

    const int tid = threadIdx.x;
    const long gp0 = (long)blockIdx.x * PTS;

    const int lane = tid & 63;
    const int wv   = tid >> 6;       // wave 0..3 -> M-tiles 2wv, 2wv+1
    const int p32  = lane & 31;
    const int hi   = lane >> 5;

    // ---------------- layer 0: (3 -> 256), Taylor-mode, fp32 VALU ----------
    {
        const int p  = tid & 31;
        const int jg = tid >> 5;     // 0..7 -> features jg*32 .. jg*32+31
        const float x  = xyt[(gp0 + p) * 3 + 0];
        const float y  = xyt[(gp0 + p) * 3 + 1];
        const float tc = xyt[(gp0 + p) * 3 + 2];
        #pragma unroll
        for (int g = 0; g < 4; ++g) {
            f16x8 vh[5], vl[5];
            #pragma unroll
            for (int c = 0; c < 8; ++c) {
                const int j = jg * 32 + g * 8 + c;
                const float wx = w0[0 * WIDTH + j];
                const float wy = w0[1 * WIDTH + j];
                const float wt = w0[2 * WIDTH + j];
                float zv, s;
                tanh_s(fmaf(x, wx, fmaf(y, wy, fmaf(tc, wt, b0[j]))), zv, s);
                const float vals[5] = { zv, s * wx, s * wy, s * wt,
                                        -2.0f * zv * s * (wx * wx + wy * wy) };
                #pragma unroll
                for (int v = 0; v < 5; ++v) {
                    _Float16 h, lo;
                    split2(vals[v], h, lo);
                    vh[v][c] = h; vl[v][c] = lo;
                }
            }
            // k-block kb = jg*4 + g, 8 consecutive k -> one f16x8 per (v,comp)
            #pragma unroll
            for (int v = 0; v < 5; ++v) {
                const int off = ((v * 32 + jg * 4 + g) * 32 + p) * 8;
                *(f16x8*)&Zs[0 * CPLANE + off] = vh[v];
                *(f16x8*)&Zs[1 * CPLANE + off] = vl[v];
            }
        }
    }
    __syncthreads();

    // ---------------- hidden layers 1..5: 32x32x16 MFMA, 2-split (3 prods) --
    const float* Bsl[5] = { b1, b2, b3, b4, b5 };

    for (int l = 0; l < 5; ++l) {
        const _Float16* Wl = wt2 + l * 2 * WPLANE;
        f32x16 acc[5][2];
        #pragma unroll
        for (int v = 0; v < 5; ++v)
            #pragma unroll
            for (int m = 0; m < 2; ++m)
                acc[v][m] = (f32x16){0.f,0.f,0.f,0.f,0.f,0.f,0.f,0.f,
                                     0.f,0.f,0.f,0.f,0.f,0.f,0.f,0.f};

        #pragma unroll 2
        for (int s = 0; s < 16; ++s) {
            f16x8 Ah[2], Al[2];
            #pragma unroll
            for (int m = 0; m < 2; ++m) {
                const int fo = (((wv * 2 + m) * 16 + s) * 64 + lane) * 8;
                Ah[m] = *(const f16x8*)(Wl + fo);
                Al[m] = *(const f16x8*)(Wl + WPLANE + fo);
            }
            #pragma unroll
            for (int v = 0; v < 5; ++v) {
                const int zo = ((v * 32 + s * 2 + hi) * 32 + p32) * 8;
                const f16x8 Bh = *(const f16x8*)&Zs[0 * CPLANE + zo];
                const f16x8 Bl = *(const f16x8*)&Zs[1 * CPLANE + zo];
                #pragma unroll
                for (int m = 0; m < 2; ++m) {
                    f32x16 a = acc[v][m];
                    a = __builtin_amdgcn_mfma_f32_32x32x16_f16(Ah[m], Bl, a, 0, 0, 0);
                    a = __builtin_amdgcn_mfma_f32_32x32x16_f16(Al[m], Bh, a, 0, 0, 0);
                    a = __builtin_amdgcn_mfma_f32_32x32x16_f16(Ah[m], Bh, a, 0, 0, 0);
                    acc[v][m] = a;
                }
            }
        }
        __syncthreads();   // all Zs reads done before overwrite

        // epilogue: lane holds (p = lane&31), rows (reg&3)+8*(reg>>2)+4*hi
        const float* Bb = Bsl[l];
        #pragma unroll
        for (int m = 0; m < 2; ++m) {
            const int Mt = wv * 2 + m;
            #pragma unroll
            for (int g = 0; g < 4; ++g) {
                const int j0 = Mt * 32 + g * 8 + hi * 4;
                float nv[5][4];
                #pragma unroll
                for (int r = 0; r < 4; ++r) {
                    const int reg = g * 4 + r;
                    float zv, s;
                    tanh_s(acc[0][m][reg] + Bb[j0 + r], zv, s);
                    const float u1 = acc[1][m][reg];
                    const float u2 = acc[2][m][reg];
                    nv[0][r] = zv;
                    nv[1][r] = s * u1;
                    nv[2][r] = s * u2;
                    nv[3][r] = s * acc[3][m][reg];
                    nv[4][r] = fmaf(-2.0f * zv * s, fmaf(u1, u1, u2 * u2),
                                    s * acc[4][m][reg]);
                }
                // write 4 consecutive k = j0..j0+3: kb = Mt*4+g, in-slot 4*hi
                const int base0 = ((Mt * 4 + g) * 32 + p32) * 8 + hi * 4;
                #pragma unroll
                for (int v = 0; v < 5; ++v) {
                    const h16x2 h01 = __builtin_amdgcn_cvt_pkrtz(nv[v][0], nv[v][1]);
                    const h16x2 h23 = __builtin_amdgcn_cvt_pkrtz(nv[v][2], nv[v][3]);
                    const h16x2 l01 = __builtin_amdgcn_cvt_pkrtz(nv[v][0] - (float)h01[0],
                                                                 nv[v][1] - (float)h01[1]);
                    const h16x2 l23 = __builtin_amdgcn_cvt_pkrtz(nv[v][2] - (float)h23[0],
                                                                 nv[v][3] - (float)h23[1]);
                    *(f16x4*)&Zs[0 * CPLANE + v * 8192 + base0] =
                        (f16x4){ (_Float16)h01[0], (_Float16)h01[1],
                                 (_Float16)h23[0], (_Float16)h23[1] };
                    *(f16x4*)&Zs[1 * CPLANE + v * 8192 + base0] =
                        (f16x4){ (_Float16)l01[0], (_Float16)l01[1],
                                 (_Float16)l23[0], (_Float16)l23[1] };
                }
            }
        }
        __syncthreads();
    }

    // ---------------- final layer: (256 -> 1) dot products ------------------
    // 160 rows (5 chains x 32 points), one thread per row, full 256-k dot.
    float partial = 0.f;
    if (tid < 5 * PTS) {
        const int v = tid >> 5, p = tid & 31;
        for (int kb = 0; kb < 32; ++kb) {
            const int off = ((v * 32 + kb) * 32 + p) * 8;
            const f16x8 zh = *(const f16x8*)&Zs[0 * CPLANE + off];
            const f16x8 zl = *(const f16x8*)&Zs[1 * CPLANE + off];
            #pragma unroll
            for (int i = 0; i < 8; ++i)
                partial = fmaf((float)zh[i] + (float)zl[i], w6[kb * 8 + i], partial);
        }
    }
    __syncthreads();                 // all reads of Zs done before aliasing
    if (tid < 5 * PTS) redf[tid] = partial;
    __syncthreads();

    // ---------------- residual ----------------
    if (tid < PTS) {
        const int p = tid;
        const float h   = redf[0 * 32 + p] + b6[0];
        const float hx  = redf[1 * 32 + p];
        const float hy  = redf[2 * 32 + p];
        const float ht  = redf[3 * 32 + p];
        const float lap = redf[4 * 32 + p];
        const float x  = xyt[(gp0 + p) * 3 + 0];
        const float y  = xyt[(gp0 + p) * 3 + 1];
        const float tc = xyt[(gp0 + p) * 3 + 2];
        const float pi = 3.14159265358979323846f;
        const float f = sinf(pi * x) * sinf(pi * y) * expf(-tc);
        out[gp0 + p] = ht - 0.5f * (fmaf(h, lap, fmaf(hx, hx, hy * hy))) - f;
    }
}

extern "C" void kernel_launch(void* const* d_in, const int* in_sizes, int n_in,
                              void* d_out, int out_size, void* d_ws, size_t ws_size,
                              hipStream_t stream) {
    const float* xyt = (const float*)d_in[0];
    const float* w0  = (const float*)d_in[1];
    const float* b0  = (const float*)d_in[2];
    const float* w1  = (const float*)d_in[3];
    const float* b1  = (const float*)d_in[4];
    const float* w2  = (const float*)d_in[5];
    const float* b2  = (const float*)d_in[6];
    const float* w3  = (const float*)d_in[7];
    const float* b3  = (const float*)d_in[8];
    const float* w4  = (const float*)d_in[9];
    const float* b4  = (const float*)d_in[10];
    const float* w5  = (const float*)d_in[11];
    const float* b5  = (const float*)d_in[12];
    const float* w6  = (const float*)d_in[13];
    const float* b6  = (const float*)d_in[14];
    float* out = (float*)d_out;
    _Float16* wt2 = (_Float16*)d_ws;    // needs 5*2*65536*2 = 1,310,720 B

    prep_w_kernel<<<160, 256, 0, stream>>>(w1, w2, w3, w4, w5, wt2);

    const int npts = in_sizes[0] / 3;   // 131072
    dim3 grid(npts / PTS);              // 4096
    dim3 block(256);
    pde_mfma_kernel<<<grid, block, 0, stream>>>(xyt, w0, b0, b1, b2, b3, b4, b5,
                                                w6, b6, wt2, out);
}